// Round 1
// 314.620 us; speedup vs baseline: 1.0440x; 1.0440x over previous
//
#include <hip/hip_runtime.h>

typedef unsigned short u16;
typedef __attribute__((ext_vector_type(8))) short s16x8;
typedef __attribute__((ext_vector_type(4))) float f32x4;
typedef __attribute__((ext_vector_type(16))) float f32x16;
typedef __attribute__((ext_vector_type(4))) unsigned short u16x4;
typedef __attribute__((ext_vector_type(4))) unsigned int u32x4;

#define MFMA16(a, b, c) __builtin_amdgcn_mfma_f32_16x16x32_bf16(a, b, c, 0, 0, 0)
#define MFMA32(a, b, c) __builtin_amdgcn_mfma_f32_32x32x16_bf16(a, b, c, 0, 0, 0)

__device__ __forceinline__ u16 f2bf(float f) {
  unsigned u = __builtin_bit_cast(unsigned, f);
  u += 0x7fffu + ((u >> 16) & 1u);  // RNE
  return (u16)(u >> 16);
}

__device__ __forceinline__ void async16(const void* g, void* l) {
  __builtin_amdgcn_global_load_lds(
      (const __attribute__((address_space(1))) void*)g,
      (__attribute__((address_space(3))) void*)l, 16, 0, 0);
}

__device__ __forceinline__ s16x8 ld8(const u16* p) { return *(const s16x8*)p; }

// packed f32x2 -> bf16x2 (RNE); no builtin on gfx950, inline asm per T12
__device__ __forceinline__ unsigned cvtpk(float lo, float hi) {
  unsigned r;
  asm("v_cvt_pk_bf16_f32 %0, %1, %2" : "=v"(r) : "v"(lo), "v"(hi));
  return r;
}

// log2(e) / sqrt(64) folded into Q at projection time
#define PRE 0.18033688011112042f

// ---------------- fused fp32 -> bf16 cast of all 5 tensors ----------------
__global__ __launch_bounds__(256) void cvt_all(
    const float* __restrict__ X, const float* __restrict__ Wq,
    const float* __restrict__ Wk, const float* __restrict__ Wv,
    const float* __restrict__ Wo, u16* __restrict__ out) {
  long e = (long)(blockIdx.x * 256 + threadIdx.x) * 4;
  const float* src;
  if (e < 8388608L) src = X + e;
  else if (e < 12582912L) src = Wq + (e - 8388608L);
  else if (e < 13631488L) src = Wk + (e - 12582912L);
  else if (e < 14680064L) src = Wv + (e - 13631488L);
  else src = Wo + (e - 14680064L);
  float4 v = *(const float4*)src;
  u16x4 o = {f2bf(v.x), f2bf(v.y), f2bf(v.z), f2bf(v.w)};
  *(u16x4*)(out + e) = o;
}

// ---------------- NT GEMM: C[m,n] = sum_k A[m,k]*B[n,k] ----------------
// 128x128 tile, BK=32, double-buffered LDS, ONE barrier per K-iter (prefetch
// issued right after the barrier -> a full compute phase to land before the
// next barrier's vmcnt drain). Tiles stored as 64 double-rows x 8 XOR-swizzled
// 16B chunks (conflict-free family, measured 0 conflicts in round 2/3).
enum { EPI_QKV = 0, EPI_OUT = 1 };

template <int EPI>
__global__ __launch_bounds__(256) void gemm_nt(
    const u16* __restrict__ A, const u16* __restrict__ Bm,
    const float* __restrict__ cosp, const float* __restrict__ sinp,
    u16* __restrict__ Qo, u16* __restrict__ Ko, u16* __restrict__ Vo,
    float* __restrict__ Co, int K) {
  // [2 buffers][A: 4096 u16 | B: 4096 u16] = 32 KB; epilogue reuses all 32 KB
  __shared__ u16 SM[16384];
  const int t = threadIdx.x;
  const int lane = t & 63;
  const int w = t >> 6, wm = w >> 1, wn = w & 1;
  const int quad = lane >> 4, c16 = lane & 15;
  const int m0 = blockIdx.y * 128, n0 = blockIdx.x * 128;

  f32x4 acc[4][4];
  const f32x4 zero = {0.f, 0.f, 0.f, 0.f};
#pragma unroll
  for (int i = 0; i < 4; ++i)
#pragma unroll
    for (int j = 0; j < 4; ++j) acc[i][j] = zero;

  // staging: chunk c (16B) of a 128x32 tile holds global
  //   double-row dr=c>>3, k8=(c&7)^(dr&7) -> (row 2dr+(k8>>2), colchunk k8&3)
  const u16* gA[2];
  const u16* gB[2];
  int lof[2];
#pragma unroll
  for (int p = 0; p < 2; ++p) {
    int c = t + p * 256;
    int dr = c >> 3, k8 = (c & 7) ^ (dr & 7);
    int row = 2 * dr + (k8 >> 2), col = (k8 & 3) * 8;
    gA[p] = A + (size_t)(m0 + row) * K + col;
    gB[p] = Bm + (size_t)(n0 + row) * K + col;
    lof[p] = c * 8;  // u16 index within a buffer half
  }

  // fragment LDS offsets (loop-invariant; toggle buffer by +8192)
  int aoff[4], boff[4];
#pragma unroll
  for (int i = 0; i < 4; ++i) {
    int rowA = wm * 64 + i * 16 + c16;
    int drA = rowA >> 1;
    int chA = (((rowA & 1) << 2) | quad) ^ (drA & 7);
    aoff[i] = drA * 64 + chA * 8;
    int rowB = wn * 64 + i * 16 + c16;
    int drB = rowB >> 1;
    int chB = (((rowB & 1) << 2) | quad) ^ (drB & 7);
    boff[i] = 4096 + drB * 64 + chB * 8;
  }

  // prologue: stage buffer 0 with k-slab 0
#pragma unroll
  for (int p = 0; p < 2; ++p) {
    async16(gA[p], &SM[lof[p]]);
    async16(gB[p], &SM[4096 + lof[p]]);
  }

  const int niter = K >> 5;
  for (int kt = 0; kt < niter; ++kt) {
    const int cb = (kt & 1) * 8192;
    __syncthreads();  // drains vmcnt: buf[cur] staged; prev reads of buf[nxt] done
    if (kt + 1 < niter) {
      const int nb = 8192 - cb;
#pragma unroll
      for (int p = 0; p < 2; ++p) {
        gA[p] += 32;
        gB[p] += 32;
        async16(gA[p], &SM[nb + lof[p]]);
        async16(gB[p], &SM[nb + 4096 + lof[p]]);
      }
    }
    s16x8 af[4], bfr[4];
#pragma unroll
    for (int i = 0; i < 4; ++i) af[i] = ld8(&SM[cb + aoff[i]]);
#pragma unroll
    for (int j = 0; j < 4; ++j) bfr[j] = ld8(&SM[cb + boff[j]]);
#pragma unroll
    for (int i = 0; i < 4; ++i)
#pragma unroll
      for (int j = 0; j < 4; ++j) acc[i][j] = MFMA16(af[i], bfr[j], acc[i][j]);
  }

  if (EPI == EPI_OUT) {
#pragma unroll
    for (int i = 0; i < 4; ++i)
#pragma unroll
      for (int r = 0; r < 4; ++r) {
        int m = m0 + wm * 64 + i * 16 + quad * 4 + r;
        float* dst = Co + (size_t)m * 2048 + n0 + wn * 64 + c16;
#pragma unroll
        for (int j = 0; j < 4; ++j) dst[j * 16] = acc[i][j][r];
      }
  } else if (n0 >= 2560) {
    // V zone: transpose via LDS -> coalesced 16B stores of V^T [B][8][64][S]
    __syncthreads();  // all K-loop LDS reads done before overwrite
#pragma unroll
    for (int i = 0; i < 4; ++i)
#pragma unroll
      for (int r = 0; r < 4; ++r) {
        int sl = wm * 64 + i * 16 + quad * 4 + r;
#pragma unroll
        for (int j = 0; j < 4; ++j) {
          int dl = wn * 64 + j * 16 + c16;
          SM[dl * 128 + (((sl >> 3) ^ (dl & 15)) * 8) + (sl & 7)] =
              f2bf(acc[i][j][r]);
        }
      }
    __syncthreads();
    int bb = m0 >> 11, m0s = m0 & 2047;
#pragma unroll
    for (int p = 0; p < 8; ++p) {
      int q = p * 256 + t;
      int dl = q >> 4, k = q & 15;
      s16x8 vrow = ld8(&SM[dl * 128 + ((k ^ (dl & 15)) * 8)]);
      int nab = n0 + dl;
      int kvh = (nab - 2560) >> 6, dh = nab & 63;
      *(s16x8*)(Vo + ((size_t)(bb * 8 + kvh) * 64 + dh) * 2048 + m0s + k * 8) =
          vrow;
    }
  } else {
    const int nbase = n0 + wn * 64;
#pragma unroll
    for (int i = 0; i < 4; ++i)
#pragma unroll
      for (int r = 0; r < 4; ++r) {
        int m = m0 + wm * 64 + i * 16 + quad * 4 + r;
        int b = m >> 11, s = m & 2047;
        if (nbase < 2048) {  // Q zone: rope + prescale, store [B][32][S][64]
          int h = nbase >> 6;
          size_t base = ((size_t)(b * 32 + h) * 2048 + s) * 64;
#pragma unroll
          for (int j = 0; j < 2; ++j) {
            int d = j * 16 + c16;
            float v1 = acc[i][j][r], v2 = acc[i][j + 2][r];
            float c1 = cosp[m * 64 + d], s1 = sinp[m * 64 + d];
            float c2 = cosp[m * 64 + d + 32], s2 = sinp[m * 64 + d + 32];
            Qo[base + d] = f2bf((v1 * c1 - v2 * s1) * PRE);
            Qo[base + d + 32] = f2bf((v2 * c2 + v1 * s2) * PRE);
          }
        } else {  // K zone: rope, store [B][8][S][64]
          int h = (nbase - 2048) >> 6;
          size_t base = ((size_t)(b * 8 + h) * 2048 + s) * 64;
#pragma unroll
          for (int j = 0; j < 2; ++j) {
            int d = j * 16 + c16;
            float v1 = acc[i][j][r], v2 = acc[i][j + 2][r];
            float c1 = cosp[m * 64 + d], s1 = sinp[m * 64 + d];
            float c2 = cosp[m * 64 + d + 32], s2 = sinp[m * 64 + d + 32];
            Ko[base + d] = f2bf(v1 * c1 - v2 * s1);
            Ko[base + d + 32] = f2bf(v2 * c2 + v1 * s2);
          }
        }
      }
  }
}

// ---------------- flash attention (causal, GQA) ----------------
// grid: (8 qt-pairs, 64 b*h). Each block does q-tiles {x, 15-x}: 34 k-iters.
// BQ=128 (4 waves x 32 rows), BKV=64. Double-buffered K/V, ONE barrier/iter.
//
// Round-1 rewrite: swapped-operand 32x32x16 MFMA (S^T = mfma(K,Q)) + fully
// in-register P via T12 (16 v_cvt_pk_bf16_f32 + 8 permlane32_swap per iter).
// The old 16x16 path spilled P through LDS: 32 ds_write_b16 + 4 ds_read_b128
// + 64 cvt VALU ops per wave-iter -> DS pipe ~66% busy, VALUBusy 55%,
// MfmaUtil 16%. Now DS ops/iter: 16 b128 reads total; lacc is one float/lane.
//
// S^T layout (m74/m101): col=lane&31 = q, row=(r&3)+8*(r>>2)+4*(lane>>5) = key.
// PV A-frag needs P[q=lane&31][k=kk*16+hi*8+(0..7)]; key (r&3)+8(r>>2)+4*hs
// == 16c2+8hi+2j+{0,1}  <=>  hs=j>>1, r>>2=2c2+hi  =>  one permlane32_swap of
// (cvtpk(p[8c2+2u],p[8c2+2u+1]), cvtpk(p[8c2+4+2u],p[8c2+5+2u])) yields
// word(u) [lo halves] and word(u+2) [hi halves] of the frag simultaneously.
//
// Fixed-m (m=0) online softmax: Q pre-scaled so |s*log2e| << 127, exp2 cannot
// overflow; masked -> exp2(-1e30) = 0. l-reduction deferred to epilogue
// (shfl_xor(32) + per-wave LDS broadcast of 1/l).
__global__ __launch_bounds__(256) void attn(const u16* __restrict__ Q,
                                            const u16* __restrict__ Kg,
                                            const u16* __restrict__ Vg,
                                            u16* __restrict__ O) {
  __shared__ u16 Ks[2][4096];   // [buf][64 keys][64 d], XOR-swizzled chunks
  __shared__ u16 Vs[2][4096];   // [buf][64 d][64 keys] (V^T), same swizzle
  __shared__ float Lred[128];   // per-wave 1/l broadcast (32 floats/wave)
  const int t = threadIdx.x;
  const int lane = t & 63;
  const int w = t >> 6;
  const int l31 = lane & 31, hi = lane >> 5;
  const int bh = blockIdx.y;
  const int b = bh >> 5, h = bh & 31;
  const int kvh = h >> 2;  // G = 4

  const u16* Qbase = Q + ((size_t)(b * 32 + h) * 2048) * 64;
  const u16* Kbase = Kg + ((size_t)(b * 8 + kvh) * 2048) * 64;
  const u16* Vbase = Vg + ((size_t)(b * 8 + kvh) * 64) * 2048;

  // staging source pre-swizzle (async16 LDS dest is linear): LDS slot t&7 of
  // row t>>3 holds global chunk (t&7)^(row&7)
  const int sr0 = t >> 3, sc0 = ((t & 7) ^ (sr0 & 7)) * 8;
  const int sr1 = (t + 256) >> 3, sc1 = (((t + 256) & 7) ^ (sr1 & 7)) * 8;

  // read-side swizzled chunk offsets: chunk (2c+hi) of row l31 (+32k)
  int off8[4];
#pragma unroll
  for (int c = 0; c < 4; ++c) off8[c] = ((2 * c + hi) ^ (l31 & 7)) * 8;
  const int rbB = l31 * 64;

  for (int ph = 0; ph < 2; ++ph) {
    const int qt = ph ? 15 - blockIdx.x : blockIdx.x;
    const int q0 = qt * 128;
    const int rbase = q0 + w * 32;
    const int qrow = rbase + l31;  // this lane's q-row (S^T column)

    // Q fragments in registers: B-operand of mfma(K,Q), lane holds
    // Q[qrow][dc*16 + hi*8 + 0..7]
    s16x8 qf[4];
#pragma unroll
    for (int dc = 0; dc < 4; ++dc)
      qf[dc] = ld8(Qbase + (size_t)qrow * 64 + dc * 16 + hi * 8);

    f32x16 oacc[2];
#pragma unroll
    for (int dn = 0; dn < 2; ++dn)
#pragma unroll
      for (int r = 0; r < 16; ++r) oacc[dn][r] = 0.f;
    float lacc = 0.f;

    const int nkt = 2 * qt + 2;

    __syncthreads();  // previous phase's LDS reads done before restaging buf0
    {
      async16(Kbase + sr0 * 64 + sc0, &Ks[0][t * 8]);
      async16(Kbase + sr1 * 64 + sc1, &Ks[0][t * 8 + 2048]);
      async16(Vbase + (size_t)sr0 * 2048 + sc0, &Vs[0][t * 8]);
      async16(Vbase + (size_t)sr1 * 2048 + sc1, &Vs[0][t * 8 + 2048]);
    }

    for (int kt = 0; kt < nkt; ++kt) {
      const int cur = kt & 1;
      __syncthreads();  // buf[cur] staged; prev reads of buf[1-cur] done
      if (kt + 1 < nkt) {
        const int nxt = 1 - cur;
        const u16* kg = Kbase + (kt + 1) * 4096;
        async16(kg + sr0 * 64 + sc0, &Ks[nxt][t * 8]);
        async16(kg + sr1 * 64 + sc1, &Ks[nxt][t * 8 + 2048]);
        async16(Vbase + (size_t)sr0 * 2048 + (kt + 1) * 64 + sc0,
                &Vs[nxt][t * 8]);
        async16(Vbase + (size_t)sr1 * 2048 + (kt + 1) * 64 + sc1,
                &Vs[nxt][t * 8 + 2048]);
      }
      const u16* Kb = Ks[cur];
      const u16* Vb = Vs[cur];

#pragma unroll
      for (int kn = 0; kn < 2; ++kn) {
        const int kb0 = kt * 64 + kn * 32;
        if (kb0 <= rbase + 31) {  // skip fully-masked 32-key tiles
          // S^T = K-tile @ Q^T
          f32x16 s_;
#pragma unroll
          for (int r = 0; r < 16; ++r) s_[r] = 0.f;
#pragma unroll
          for (int dc = 0; dc < 4; ++dc) {
            s16x8 kf = ld8(&Kb[kn * 2048 + rbB + off8[dc]]);
            s_ = MFMA32(kf, qf[dc], s_);
          }
          if (kb0 + 31 > rbase) {  // causal mask on diagonal tiles
            const int kb = kb0 + 4 * hi;
#pragma unroll
            for (int r = 0; r < 16; ++r)
              if (kb + (r & 3) + 8 * (r >> 2) > qrow) s_[r] = -1e30f;
          }
          float p[16];
#pragma unroll
          for (int r = 0; r < 16; ++r) p[r] = __builtin_amdgcn_exp2f(s_[r]);
          {  // l accumulation: balanced tree, one accumulator per lane
            float e0 = p[0] + p[1], e1 = p[2] + p[3], e2 = p[4] + p[5],
                  e3 = p[6] + p[7], e4 = p[8] + p[9], e5 = p[10] + p[11],
                  e6 = p[12] + p[13], e7 = p[14] + p[15];
            lacc += ((e0 + e1) + (e2 + e3)) + ((e4 + e5) + (e6 + e7));
          }
          // T12: build PV A-frags in-register, then immediately consume
#pragma unroll
          for (int c2 = 0; c2 < 2; ++c2) {
            unsigned a0 = cvtpk(p[8 * c2 + 0], p[8 * c2 + 1]);
            unsigned b0 = cvtpk(p[8 * c2 + 4], p[8 * c2 + 5]);
            unsigned a1 = cvtpk(p[8 * c2 + 2], p[8 * c2 + 3]);
            unsigned b1 = cvtpk(p[8 * c2 + 6], p[8 * c2 + 7]);
            auto s0 = __builtin_amdgcn_permlane32_swap(a0, b0, false, false);
            auto s1 = __builtin_amdgcn_permlane32_swap(a1, b1, false, false);
            u32x4 fw = {(unsigned)s0[0], (unsigned)s1[0], (unsigned)s0[1],
                        (unsigned)s1[1]};
            s16x8 F = __builtin_bit_cast(s16x8, fw);
            const int kk = 2 * kn + c2;
#pragma unroll
            for (int dn = 0; dn < 2; ++dn) {
              s16x8 vf = ld8(&Vb[dn * 2048 + rbB + off8[kk]]);
              oacc[dn] = MFMA32(F, vf, oacc[dn]);
            }
          }
        }
      }
    }

    // epilogue: l lives per-lane split across hi halves -> one shfl_xor(32),
    // broadcast 1/l through wave-private LDS, scale + store O
    {
      float ltot = lacc + __shfl_xor(lacc, 32);
      if (lane < 32) Lred[w * 32 + l31] = 1.f / ltot;
      f32x4 lv[4];
#pragma unroll
      for (int g = 0; g < 4; ++g)
        lv[g] = *(const f32x4*)&Lred[w * 32 + 8 * g + 4 * hi];
#pragma unroll
      for (int dn = 0; dn < 2; ++dn)
#pragma unroll
        for (int g = 0; g < 4; ++g)
#pragma unroll
          for (int j = 0; j < 4; ++j) {
            int s = rbase + 8 * g + 4 * hi + j;  // = D-row (r&3)+8(r>>2)+4hi
            O[((size_t)(b * 2048 + s)) * 2048 + h * 64 + dn * 32 + l31] =
                f2bf(oacc[dn][4 * g + j] * lv[g][j]);
          }
    }
  }
}

// ---------------- launch ----------------
extern "C" void kernel_launch(void* const* d_in, const int* in_sizes, int n_in,
                              void* d_out, int out_size, void* d_ws,
                              size_t ws_size, hipStream_t stream) {
  const float* X = (const float*)d_in[0];
  const float* cosp = (const float*)d_in[1];
  const float* sinp = (const float*)d_in[2];
  const float* Wq = (const float*)d_in[4];
  const float* Wk = (const float*)d_in[5];
  const float* Wv = (const float*)d_in[6];
  const float* Wo = (const float*)d_in[7];
  float* out = (float*)d_out;

  u16* Xb = (u16*)d_ws;       // 8,388,608
  u16* Wqkv = Xb + 8388608;   // 3072x2048 (Wq|Wk|Wv rows)
  u16* Wob = Wqkv + 6291456;  // 4,194,304
  u16* Qr = Wob + 4194304;    // [2][32][2048][64]  (pre-scaled)
  u16* Kr = Qr + 8388608;     // [2][8][2048][64]
  u16* Vt = Kr + 2097152;     // [2][8][64][2048]
  u16* Ob = Vt + 2097152;     // [2][2048][2048]

  cvt_all<<<18432, 256, 0, stream>>>(X, Wq, Wk, Wv, Wo, Xb);

  gemm_nt<EPI_QKV><<<dim3(24, 32), 256, 0, stream>>>(
      Xb, Wqkv, cosp, sinp, Qr, Kr, Vt, nullptr, 2048);

  attn<<<dim3(8, 64), 256, 0, stream>>>(Qr, Kr, Vt, Ob);

  gemm_nt<EPI_OUT><<<dim3(16, 32), 256, 0, stream>>>(
      Ob, Wob, nullptr, nullptr, nullptr, nullptr, nullptr, out, 2048);
}